// Round 5
// baseline (261.260 us; speedup 1.0000x reference)
//
#include <hip/hip_runtime.h>
#include <hip/hip_bf16.h>
#include <stdint.h>

#define HEADS 8
#define DHEAD 64
#define DIM 512
#define NSEQ 2048
#define BATCH 2
#define NROWS (BATCH * NSEQ)      // 4096
#define QKV_N 1536
#define REL_ROWS 1025
#define REL_PITCH 1088            // padded to 17*64 so qrel GEMM needs no N-bounds
#define NSPLIT 2
#define KV_PER_SPLIT (NSEQ / NSPLIT)   // 1024

static constexpr float SCALE_LOG2E = 0.125f * 1.4426950408889634f;  // SCALE * log2(e)

typedef __attribute__((ext_vector_type(8))) short bf16x8;   // 8 bf16 (4 VGPRs)
typedef __attribute__((ext_vector_type(4))) float f32x4;

__device__ __forceinline__ uint16_t f2bf(float f) {
    union { float f; uint32_t u; } v{f};
    uint32_t r = (v.u + 0x7FFFu + ((v.u >> 16) & 1u)) >> 16;
    return (uint16_t)r;
}
__device__ __forceinline__ float bf2f(uint16_t u) {
    union { uint32_t u; float f; } v{(uint32_t)u << 16};
    return v.f;
}

// ---------------------------------------------------------------- prep: x->bf16, rel_emb->bf16 (padded)
__global__ void prep_misc(const float* __restrict__ x, const float* __restrict__ rel,
                          uint16_t* __restrict__ xb, uint16_t* __restrict__ relb) {
    int total = NROWS * DIM + REL_PITCH * DHEAD;
    for (int idx = blockIdx.x * blockDim.x + threadIdx.x; idx < total; idx += gridDim.x * blockDim.x) {
        if (idx < NROWS * DIM) {
            xb[idx] = f2bf(x[idx]);
        } else {
            int i2 = idx - NROWS * DIM;
            relb[i2] = (i2 < REL_ROWS * DHEAD) ? f2bf(rel[i2]) : (uint16_t)0;
        }
    }
}

// ---------------------------------------------------------------- prep: transpose weights to [out][in] bf16
__global__ void prep_w(const float* __restrict__ Wq, const float* __restrict__ Wkv,
                       const float* __restrict__ Wo,
                       uint16_t* __restrict__ Wqkv_t, uint16_t* __restrict__ Wo_t) {
    __shared__ float tile[32][33];
    int bid = blockIdx.x;
    const float* src; uint16_t* dst; int J, ti, tj;
    if (bid < 256)      { src = Wq;  dst = Wqkv_t;             J = 512;  ti = bid >> 4;        tj = bid & 15; }
    else if (bid < 768) { int b = bid - 256; src = Wkv; dst = Wqkv_t + 512 * 512; J = 1024; ti = b >> 5; tj = b & 31; }
    else                { int b = bid - 768; src = Wo;  dst = Wo_t;   J = 512;  ti = b >> 4;        tj = b & 15; }
    int tx = threadIdx.x & 31, ty = threadIdx.x >> 5;
    int k0 = ti * 32, j0 = tj * 32;
    #pragma unroll
    for (int i = 0; i < 4; i++) tile[ty + 8 * i][tx] = src[(size_t)(k0 + ty + 8 * i) * J + j0 + tx];
    __syncthreads();
    #pragma unroll
    for (int i = 0; i < 4; i++) dst[(size_t)(j0 + ty + 8 * i) * 512 + k0 + tx] = f2bf(tile[tx][ty + 8 * i]);
}

// ---------------------------------------------------------------- 128x128 MFMA GEMM: C = A[M,K] * Bt[N,K]^T
template <bool BF16_OUT>
__global__ __launch_bounds__(256) void gemm128(const uint16_t* __restrict__ A,
                                               const uint16_t* __restrict__ Bt,
                                               void* __restrict__ Cout,
                                               const float* __restrict__ bias,
                                               int K, int ldc) {
    __shared__ char lds[32768];
    char* ldsA = lds;
    char* ldsB = lds + 16384;
    int m0 = blockIdx.x * 128, n0 = blockIdx.y * 128;
    int t = threadIdx.x, lane = t & 63, w = t >> 6;
    int wr = w >> 1, wc = w & 1;
    int l15 = lane & 15, lh = lane >> 4;
    f32x4 acc[4][4] = {};
    for (int k0 = 0; k0 < K; k0 += 64) {
        __syncthreads();
        {
            int row = t >> 3, ch = t & 7;
            #pragma unroll
            for (int p = 0; p < 4; p++) {
                int r = row + 32 * p;
                bf16x8 va = *(const bf16x8*)(A + (size_t)(m0 + r) * K + k0 + ch * 8);
                *(bf16x8*)(ldsA + r * 128 + ((ch * 16) ^ ((r & 7) << 4))) = va;
                bf16x8 vb = *(const bf16x8*)(Bt + (size_t)(n0 + r) * K + k0 + ch * 8);
                *(bf16x8*)(ldsB + r * 128 + ((ch * 16) ^ ((r & 7) << 4))) = vb;
            }
        }
        __syncthreads();
        #pragma unroll
        for (int kk = 0; kk < 2; kk++) {
            bf16x8 a[4], b[4];
            #pragma unroll
            for (int mi = 0; mi < 4; mi++) {
                int m = wr * 64 + mi * 16 + l15;
                a[mi] = *(const bf16x8*)(ldsA + m * 128 + ((kk * 64 + lh * 16) ^ ((m & 7) << 4)));
            }
            #pragma unroll
            for (int ni = 0; ni < 4; ni++) {
                int n = wc * 64 + ni * 16 + l15;
                b[ni] = *(const bf16x8*)(ldsB + n * 128 + ((kk * 64 + lh * 16) ^ ((n & 7) << 4)));
            }
            #pragma unroll
            for (int mi = 0; mi < 4; mi++)
                #pragma unroll
                for (int ni = 0; ni < 4; ni++)
                    acc[mi][ni] = __builtin_amdgcn_mfma_f32_16x16x32_bf16(a[mi], b[ni], acc[mi][ni], 0, 0, 0);
        }
    }
    #pragma unroll
    for (int mi = 0; mi < 4; mi++)
        #pragma unroll
        for (int ni = 0; ni < 4; ni++)
            #pragma unroll
            for (int i = 0; i < 4; i++) {
                int m = m0 + wr * 64 + mi * 16 + lh * 4 + i;
                int n = n0 + wc * 64 + ni * 16 + l15;
                float v = acc[mi][ni][i];
                if constexpr (BF16_OUT) ((uint16_t*)Cout)[(size_t)m * ldc + n] = f2bf(v);
                else                    ((float*)Cout)[(size_t)m * ldc + n] = v + bias[n];
            }
}

// ---------------------------------------------------------------- qrel[h, r, p] = q_h[r,:] . rel_emb[p,:]
__global__ __launch_bounds__(256) void qrel_gemm(const uint16_t* __restrict__ QKV,
                                                 const uint16_t* __restrict__ relb,
                                                 uint16_t* __restrict__ qrel) {
    __shared__ char lds[16384];
    char* ldsA = lds;
    char* ldsB = lds + 8192;
    int h = blockIdx.y;
    int r0 = blockIdx.x * 64;
    int t = threadIdx.x, lane = t & 63, w = t >> 6;
    int l15 = lane & 15, lh = lane >> 4;
    {
        int row = t >> 3, ch = t & 7;
        #pragma unroll
        for (int p = 0; p < 2; p++) {
            int r = row + 32 * p;
            bf16x8 v = *(const bf16x8*)(QKV + (size_t)(r0 + r) * QKV_N + h * 64 + ch * 8);
            *(bf16x8*)(ldsA + r * 128 + ((ch * 16) ^ ((r & 7) << 4))) = v;
        }
    }
    __syncthreads();
    bf16x8 afrag[2];
    #pragma unroll
    for (int kk = 0; kk < 2; kk++) {
        int m = w * 16 + l15;
        afrag[kk] = *(const bf16x8*)(ldsA + m * 128 + ((kk * 64 + lh * 16) ^ ((m & 7) << 4)));
    }
    for (int pb = 0; pb < REL_PITCH / 64; pb++) {
        int p0 = pb * 64;
        __syncthreads();
        {
            int row = t >> 3, ch = t & 7;
            #pragma unroll
            for (int p = 0; p < 2; p++) {
                int r = row + 32 * p;
                bf16x8 v = *(const bf16x8*)(relb + (size_t)(p0 + r) * 64 + ch * 8);
                *(bf16x8*)(ldsB + r * 128 + ((ch * 16) ^ ((r & 7) << 4))) = v;
            }
        }
        __syncthreads();
        f32x4 acc[4] = {};
        #pragma unroll
        for (int kk = 0; kk < 2; kk++)
            #pragma unroll
            for (int ni = 0; ni < 4; ni++) {
                int n = ni * 16 + l15;
                bf16x8 b = *(const bf16x8*)(ldsB + n * 128 + ((kk * 64 + lh * 16) ^ ((n & 7) << 4)));
                acc[ni] = __builtin_amdgcn_mfma_f32_16x16x32_bf16(afrag[kk], b, acc[ni], 0, 0, 0);
            }
        #pragma unroll
        for (int ni = 0; ni < 4; ni++)
            #pragma unroll
            for (int i = 0; i < 4; i++) {
                int rr = r0 + w * 16 + lh * 4 + i;
                int p = p0 + ni * 16 + l15;
                qrel[((size_t)h * NROWS + rr) * REL_PITCH + p] = f2bf(acc[ni][i]);
            }
    }
}

// ---------------------------------------------------------------- flash attention: QBLK=64, 4 waves,
//   coalesced qrel-window LDS staging, single-buffer K/V/W with 2 barriers, 4 blocks/CU
__global__ __launch_bounds__(256, 4) void attn_kernel(const uint16_t* __restrict__ QKV,
                                                      const uint16_t* __restrict__ qrel,
                                                      float* __restrict__ Opart,
                                                      float* __restrict__ mlpart) {
    __shared__ __align__(16) char lds[35328];
    char* ldsQ = lds;            // 8 KB: Q stage -> P (4 waves x 2 KB)
    char* ldsK = lds + 8192;     // 8 KB [64][128] swz
    char* ldsV = lds + 16384;    // 10 KB [80][128]: rows 64..79 const (row 64 = ones)
    char* ldsW = lds + 26624;    // 8704 B: qrel windows [64][68] (pitch 136 B)

    // XCD-chunked bijective remap (1024 % 8 == 0): each XCD gets 128 consecutive x
    int flat = blockIdx.x + 32 * (blockIdx.y + 8 * blockIdx.z);   // 1024 blocks
    int x = (flat & 7) * 128 + (flat >> 3);
    int qb = x & 31, h = (x >> 5) & 7, z = x >> 8;
    int b = z >> 1, sp = z & 1;

    int t = threadIdx.x, lane = t & 63, w = t >> 6;
    int l15 = lane & 15, lh = lane >> 4;
    int r4 = t >> 2, q4 = t & 3;          // staging: row 0..63, 32B chunk 0..3
    int n0 = qb * 64;
    int kvbase = sp * KV_PER_SPLIT;

    // ones rows for V^T rows 64..79 (row 64 = 1.0 -> l accumulator; 65..79 = 0)
    {
        int rr = t >> 4, e = t & 15;
        uint32_t val = (rr == 0) ? 0x3F803F80u : 0u;
        *(uint32_t*)(ldsV + 8192 + rr * 128 + e * 8)     = val;
        *(uint32_t*)(ldsV + 8192 + rr * 128 + e * 8 + 4) = val;
    }

    // stage Q 64x64 (swizzled)
    {
        size_t rowQ = (size_t)b * NSEQ + n0;
        const uint16_t* src = QKV + (rowQ + r4) * QKV_N + h * 64 + q4 * 16;
        bf16x8 v0 = *(const bf16x8*)(src);
        bf16x8 v1 = *(const bf16x8*)(src + 8);
        int sw = (r4 & 7) << 4;
        *(bf16x8*)(ldsQ + r4 * 128 + ((q4 * 32) ^ sw))      = v0;
        *(bf16x8*)(ldsQ + r4 * 128 + ((q4 * 32 + 16) ^ sw)) = v1;
    }
    __syncthreads();
    bf16x8 qf[2];
    #pragma unroll
    for (int kk = 0; kk < 2; kk++) {
        int m = w * 16 + l15;
        qf[kk] = *(const bf16x8*)(ldsQ + m * 128 + ((kk * 64 + lh * 16) ^ ((m & 7) << 4)));
    }
    char* myP = ldsQ + w * 2048;          // P overlays dead Q region

    f32x4 oacc[5] = {};                   // [0..3] O cols, [4] l-column (col 64)
    float mrow[4];
    #pragma unroll
    for (int i = 0; i < 4; i++) mrow[i] = -INFINITY;

    // per-thread global staging pointers
    const uint16_t* gK = QKV + ((size_t)b * NSEQ + kvbase + r4) * QKV_N + 512 + h * 64 + q4 * 16;
    const uint16_t* gV = gK + 512;
    const uint16_t* qrow_n = qrel + ((size_t)h * NROWS + (size_t)b * NSEQ + n0 + r4) * REL_PITCH + 512;

    bf16x8 kr[2], vr[2], wr[2];
    auto load_kv = [&](int tile) {
        size_t off = (size_t)tile * 64 * QKV_N;
        kr[0] = *(const bf16x8*)(gK + off);
        kr[1] = *(const bf16x8*)(gK + off + 8);
        vr[0] = *(const bf16x8*)(gV + off);
        vr[1] = *(const bf16x8*)(gV + off + 8);
    };
    auto load_w = [&](int tile) {
        int kv0 = kvbase + tile * 64;
        int base = (n0 + r4) - kv0 - 63;          // d at window col 0
        #pragma unroll
        for (int p = 0; p < 2; p++) {
            int dlo = base + q4 * 16 + p * 8;
            if (dlo >= -512 && dlo <= 505) {
                wr[p] = *(const bf16x8*)(qrow_n + dlo);
            } else {
                #pragma unroll
                for (int e = 0; e < 8; e++) {
                    int d = dlo + e;
                    d = d < -512 ? -512 : (d > 512 ? 512 : d);
                    wr[p][e] = (short)qrow_n[d];
                }
            }
        }
    };
    auto scatter_all = [&]() {
        int sw = (r4 & 7) << 4;
        #pragma unroll
        for (int p = 0; p < 2; p++)
            *(bf16x8*)(ldsK + r4 * 128 + ((q4 * 32 + 16 * p) ^ sw)) = kr[p];
        #pragma unroll
        for (int p = 0; p < 2; p++)
            #pragma unroll
            for (int dd = 0; dd < 8; dd++) {
                int d = q4 * 16 + p * 8 + dd;
                int sd = (d & 7) ^ ((d >> 3) & 7);
                *(uint16_t*)(ldsV + d * 128 + 2 * (r4 ^ (sd << 3))) = (uint16_t)vr[p][dd];
            }
        #pragma unroll
        for (int p = 0; p < 2; p++)
            *(bf16x8*)(ldsW + r4 * 136 + (q4 * 16 + p * 8) * 2) = wr[p];
    };

    const int NT = KV_PER_SPLIT / 64;   // 16
    load_kv(0);
    load_w(0);
    scatter_all();

    #pragma unroll 1
    for (int tt = 0; tt < NT; ++tt) {
        __syncthreads();                               // tile tt staged & visible
        bool pf = (tt + 1 < NT);
        if (pf) { load_kv(tt + 1); load_w(tt + 1); }   // async global loads

        // bias reads from qrelW (issued early, consumed after QK^T)
        uint16_t gb[16];
        #pragma unroll
        for (int nf = 0; nf < 4; nf++)
            #pragma unroll
            for (int i = 0; i < 4; i++)
                gb[nf * 4 + i] = *(const uint16_t*)(ldsW + (w * 16 + lh * 4 + i) * 136
                                                    + (63 - nf * 16 - l15) * 2);

        // S = Q K^T
        f32x4 sacc[4] = {};
        __builtin_amdgcn_s_setprio(1);
        #pragma unroll
        for (int kk = 0; kk < 2; kk++)
            #pragma unroll
            for (int nf = 0; nf < 4; nf++) {
                int n = nf * 16 + l15;
                bf16x8 kfv = *(const bf16x8*)(ldsK + n * 128 + ((kk * 64 + lh * 16) ^ ((n & 7) << 4)));
                sacc[nf] = __builtin_amdgcn_mfma_f32_16x16x32_bf16(qf[kk], kfv, sacc[nf], 0, 0, 0);
            }
        __builtin_amdgcn_s_setprio(0);

        // + relative-position bias (raw, unscaled)
        #pragma unroll
        for (int nf = 0; nf < 4; nf++)
            #pragma unroll
            for (int i = 0; i < 4; i++)
                sacc[nf][i] += bf2f(gb[nf * 4 + i]);

        // defer-max gate: zero cross-lane ops on the common path
        float lmax = sacc[0][0];
        #pragma unroll
        for (int nf = 0; nf < 4; nf++)
            #pragma unroll
            for (int i = 0; i < 4; i++) lmax = fmaxf(lmax, sacc[nf][i]);
        float mmin = fminf(fminf(mrow[0], mrow[1]), fminf(mrow[2], mrow[3]));
        if (!__all(lmax <= mmin + 64.0f)) {   // rare: accurate row maxes + rescale
            #pragma unroll
            for (int i = 0; i < 4; i++) {
                float mx = fmaxf(fmaxf(sacc[0][i], sacc[1][i]), fmaxf(sacc[2][i], sacc[3][i]));
                mx = fmaxf(mx, __shfl_xor(mx, 1));
                mx = fmaxf(mx, __shfl_xor(mx, 2));
                mx = fmaxf(mx, __shfl_xor(mx, 4));
                mx = fmaxf(mx, __shfl_xor(mx, 8));
                float mnew = fmaxf(mrow[i], mx);
                float alpha = exp2f((mrow[i] - mnew) * SCALE_LOG2E);
                mrow[i] = mnew;
                #pragma unroll
                for (int nf = 0; nf < 5; nf++) oacc[nf][i] *= alpha;
            }
        }

        // P = exp2((S - m)*c) -> bf16 (cvt_pk RTNE) -> LDS
        #pragma unroll
        for (int i = 0; i < 4; i++) {
            int r = lh * 4 + i;
            int rsw = (r & 7) << 4;
            #pragma unroll
            for (int nf = 0; nf < 4; nf++) {
                float p = exp2f((sacc[nf][i] - mrow[i]) * SCALE_LOG2E);
                uint32_t pb;
                asm("v_cvt_pk_bf16_f32 %0, %1, %2" : "=v"(pb) : "v"(p), "v"(p));
                *(uint16_t*)(myP + r * 128 + (((nf * 16 + l15) * 2) ^ rsw)) = (uint16_t)pb;
            }
        }

        asm volatile("s_waitcnt lgkmcnt(0)" ::: "memory");
        __builtin_amdgcn_sched_barrier(0);
        __builtin_amdgcn_s_setprio(1);
        #pragma unroll
        for (int kk = 0; kk < 2; kk++) {
            bf16x8 pa = *(const bf16x8*)(myP + l15 * 128 + ((kk * 64 + lh * 16) ^ ((l15 & 7) << 4)));
            #pragma unroll
            for (int nf = 0; nf < 5; nf++) {      // nf==4: ones row -> l
                int d = nf * 16 + l15;
                int sd = (d & 7) ^ ((d >> 3) & 7);
                bf16x8 vb = *(const bf16x8*)(ldsV + d * 128 + 16 * ((kk * 4 + lh) ^ sd));
                oacc[nf] = __builtin_amdgcn_mfma_f32_16x16x32_bf16(pa, vb, oacc[nf], 0, 0, 0);
            }
        }
        __builtin_amdgcn_s_setprio(0);

        __syncthreads();                    // all reads of tile tt done
        if (pf) scatter_all();              // write tile tt+1 (waits vmcnt)
    }

    // epilogue: unnormalized partial O (f32) + m/l per row (l = oacc[4], col 64 -> l15==0)
    size_t rbase = ((size_t)(sp * BATCH + b) * HEADS + h) * NSEQ;
    #pragma unroll
    for (int nf = 0; nf < 4; nf++)
        #pragma unroll
        for (int i = 0; i < 4; i++) {
            int r = n0 + w * 16 + lh * 4 + i;
            Opart[(rbase + r) * 64 + nf * 16 + l15] = oacc[nf][i];
        }
    if (l15 == 0) {
        #pragma unroll
        for (int i = 0; i < 4; i++) {
            int r = n0 + w * 16 + lh * 4 + i;
            mlpart[(rbase + r) * 2]     = mrow[i];
            mlpart[(rbase + r) * 2 + 1] = oacc[4][i];
        }
    }
}

// ---------------------------------------------------------------- combine the 2 KV-splits
__global__ __launch_bounds__(256) void combine_kernel(const float* __restrict__ Opart,
                                                      const float* __restrict__ mlpart,
                                                      uint16_t* __restrict__ attO) {
    int lane = threadIdx.x & 63;
    int R = blockIdx.x * 4 + (threadIdx.x >> 6);   // [0, 32768): (b*8+h)*2048 + n
    const int SPSTRIDE = BATCH * HEADS * NSEQ;     // 32768
    float m1 = mlpart[(size_t)R * 2], l1 = mlpart[(size_t)R * 2 + 1];
    float m2 = mlpart[((size_t)SPSTRIDE + R) * 2], l2 = mlpart[((size_t)SPSTRIDE + R) * 2 + 1];
    float M = fmaxf(m1, m2);
    float w1 = exp2f((m1 - M) * SCALE_LOG2E);
    float w2 = exp2f((m2 - M) * SCALE_LOG2E);
    float Linv = 1.f / (l1 * w1 + l2 * w2);
    float o1 = Opart[(size_t)R * 64 + lane];
    float o2 = Opart[((size_t)SPSTRIDE + R) * 64 + lane];
    float o = (o1 * w1 + o2 * w2) * Linv;
    int bh = R >> 11, n = R & 2047;
    int b = bh >> 3, hh = bh & 7;
    attO[((size_t)(b * NSEQ + n)) * DIM + hh * 64 + lane] = f2bf(o);
}

// ---------------------------------------------------------------- launch
extern "C" void kernel_launch(void* const* d_in, const int* in_sizes, int n_in,
                              void* d_out, int out_size, void* d_ws, size_t ws_size,
                              hipStream_t stream) {
    const float* x   = (const float*)d_in[0];
    const float* Wq  = (const float*)d_in[1];
    const float* Wkv = (const float*)d_in[2];
    const float* Wo  = (const float*)d_in[3];
    const float* bo  = (const float*)d_in[4];
    const float* rel = (const float*)d_in[5];
    char* ws = (char*)d_ws;
    uint16_t* Xb     = (uint16_t*)(ws);                 // 4096*512*2      = 4,194,304 (dead after QKV gemm)
    float*    mlp    = (float*)(ws);                    // 65536*2*4      = 524,288 (reuses Xb region)
    uint16_t* Wqkv_t = (uint16_t*)(ws + 4194304);       // 1536*512*2     = 1,572,864
    uint16_t* Wo_t   = (uint16_t*)(ws + 5767168);       // 512*512*2      = 524,288
    uint16_t* relb   = (uint16_t*)(ws + 6291456);       // 1088*64*2      = 139,264
    uint16_t* QKV    = (uint16_t*)(ws + 6430720);       // 4096*1536*2    = 12,582,912
    uint16_t* attO   = (uint16_t*)(ws + 19013632);      // 4096*512*2     = 4,194,304
    uint16_t* qrel   = (uint16_t*)(ws + 23207936);      // 8*4096*1088*2  = 71,303,168
    float*    Opart  = (float*)(ws + 94511104);         // 2*32768*64*4   = 16,777,216  (end 111,288,320)

    prep_misc<<<2048, 256, 0, stream>>>(x, rel, Xb, relb);
    prep_w<<<1024, 256, 0, stream>>>(Wq, Wkv, Wo, Wqkv_t, Wo_t);
    gemm128<true><<<dim3(32, 12), 256, 0, stream>>>(Xb, Wqkv_t, QKV, nullptr, 512, QKV_N);
    qrel_gemm<<<dim3(64, 8), 256, 0, stream>>>(QKV, relb, qrel);
    attn_kernel<<<dim3(32, 8, 4), 256, 0, stream>>>(QKV, qrel, Opart, mlp);
    combine_kernel<<<8192, 256, 0, stream>>>(Opart, mlp, attO);
    gemm128<false><<<dim3(32, 4), 256, 0, stream>>>(attO, Wo_t, (float*)d_out, bo, 512, DIM);
}

// Round 6
// 158.963 us; speedup vs baseline: 1.6435x; 1.6435x over previous
//
#include <hip/hip_runtime.h>
#include <hip/hip_bf16.h>
#include <stdint.h>

#define HEADS 8
#define DHEAD 64
#define DIM 512
#define NSEQ 2048
#define BATCH 2
#define NROWS (BATCH * NSEQ)      // 4096
#define QKV_N 1536
#define REL_ROWS 1025
#define REL_PITCH 1088            // padded to 17*64 so qrel GEMM needs no N-bounds
#define NSPLIT 2
#define KV_PER_SPLIT (NSEQ / NSPLIT)   // 1024

static constexpr float SCALE_LOG2E = 0.125f * 1.4426950408889634f;  // SCALE * log2(e)

typedef __attribute__((ext_vector_type(8))) short bf16x8;   // 8 bf16 (4 VGPRs)
typedef __attribute__((ext_vector_type(4))) float f32x4;

__device__ __forceinline__ uint16_t f2bf(float f) {
    union { float f; uint32_t u; } v{f};
    uint32_t r = (v.u + 0x7FFFu + ((v.u >> 16) & 1u)) >> 16;
    return (uint16_t)r;
}
__device__ __forceinline__ float bf2f(uint16_t u) {
    union { uint32_t u; float f; } v{(uint32_t)u << 16};
    return v.f;
}

// ---------------------------------------------------------------- prep: x->bf16, rel_emb->bf16 (padded)
__global__ void prep_misc(const float* __restrict__ x, const float* __restrict__ rel,
                          uint16_t* __restrict__ xb, uint16_t* __restrict__ relb) {
    int total = NROWS * DIM + REL_PITCH * DHEAD;
    for (int idx = blockIdx.x * blockDim.x + threadIdx.x; idx < total; idx += gridDim.x * blockDim.x) {
        if (idx < NROWS * DIM) {
            xb[idx] = f2bf(x[idx]);
        } else {
            int i2 = idx - NROWS * DIM;
            relb[i2] = (i2 < REL_ROWS * DHEAD) ? f2bf(rel[i2]) : (uint16_t)0;
        }
    }
}

// ---------------------------------------------------------------- prep: transpose weights to [out][in] bf16
__global__ void prep_w(const float* __restrict__ Wq, const float* __restrict__ Wkv,
                       const float* __restrict__ Wo,
                       uint16_t* __restrict__ Wqkv_t, uint16_t* __restrict__ Wo_t) {
    __shared__ float tile[32][33];
    int bid = blockIdx.x;
    const float* src; uint16_t* dst; int J, ti, tj;
    if (bid < 256)      { src = Wq;  dst = Wqkv_t;             J = 512;  ti = bid >> 4;        tj = bid & 15; }
    else if (bid < 768) { int b = bid - 256; src = Wkv; dst = Wqkv_t + 512 * 512; J = 1024; ti = b >> 5; tj = b & 31; }
    else                { int b = bid - 768; src = Wo;  dst = Wo_t;   J = 512;  ti = b >> 4;        tj = b & 15; }
    int tx = threadIdx.x & 31, ty = threadIdx.x >> 5;
    int k0 = ti * 32, j0 = tj * 32;
    #pragma unroll
    for (int i = 0; i < 4; i++) tile[ty + 8 * i][tx] = src[(size_t)(k0 + ty + 8 * i) * J + j0 + tx];
    __syncthreads();
    #pragma unroll
    for (int i = 0; i < 4; i++) dst[(size_t)(j0 + ty + 8 * i) * 512 + k0 + tx] = f2bf(tile[tx][ty + 8 * i]);
}

// ---------------------------------------------------------------- 128x128 MFMA GEMM: C = A[M,K] * Bt[N,K]^T
template <bool BF16_OUT>
__global__ __launch_bounds__(256) void gemm128(const uint16_t* __restrict__ A,
                                               const uint16_t* __restrict__ Bt,
                                               void* __restrict__ Cout,
                                               const float* __restrict__ bias,
                                               int K, int ldc) {
    __shared__ char lds[32768];
    char* ldsA = lds;
    char* ldsB = lds + 16384;
    int m0 = blockIdx.x * 128, n0 = blockIdx.y * 128;
    int t = threadIdx.x, lane = t & 63, w = t >> 6;
    int wr = w >> 1, wc = w & 1;
    int l15 = lane & 15, lh = lane >> 4;
    f32x4 acc[4][4] = {};
    for (int k0 = 0; k0 < K; k0 += 64) {
        __syncthreads();
        {
            int row = t >> 3, ch = t & 7;
            #pragma unroll
            for (int p = 0; p < 4; p++) {
                int r = row + 32 * p;
                bf16x8 va = *(const bf16x8*)(A + (size_t)(m0 + r) * K + k0 + ch * 8);
                *(bf16x8*)(ldsA + r * 128 + ((ch * 16) ^ ((r & 7) << 4))) = va;
                bf16x8 vb = *(const bf16x8*)(Bt + (size_t)(n0 + r) * K + k0 + ch * 8);
                *(bf16x8*)(ldsB + r * 128 + ((ch * 16) ^ ((r & 7) << 4))) = vb;
            }
        }
        __syncthreads();
        #pragma unroll
        for (int kk = 0; kk < 2; kk++) {
            bf16x8 a[4], b[4];
            #pragma unroll
            for (int mi = 0; mi < 4; mi++) {
                int m = wr * 64 + mi * 16 + l15;
                a[mi] = *(const bf16x8*)(ldsA + m * 128 + ((kk * 64 + lh * 16) ^ ((m & 7) << 4)));
            }
            #pragma unroll
            for (int ni = 0; ni < 4; ni++) {
                int n = wc * 64 + ni * 16 + l15;
                b[ni] = *(const bf16x8*)(ldsB + n * 128 + ((kk * 64 + lh * 16) ^ ((n & 7) << 4)));
            }
            #pragma unroll
            for (int mi = 0; mi < 4; mi++)
                #pragma unroll
                for (int ni = 0; ni < 4; ni++)
                    acc[mi][ni] = __builtin_amdgcn_mfma_f32_16x16x32_bf16(a[mi], b[ni], acc[mi][ni], 0, 0, 0);
        }
    }
    #pragma unroll
    for (int mi = 0; mi < 4; mi++)
        #pragma unroll
        for (int ni = 0; ni < 4; ni++)
            #pragma unroll
            for (int i = 0; i < 4; i++) {
                int m = m0 + wr * 64 + mi * 16 + lh * 4 + i;
                int n = n0 + wc * 64 + ni * 16 + l15;
                float v = acc[mi][ni][i];
                if constexpr (BF16_OUT) ((uint16_t*)Cout)[(size_t)m * ldc + n] = f2bf(v);
                else                    ((float*)Cout)[(size_t)m * ldc + n] = v + bias[n];
            }
}

// ---------------------------------------------------------------- qrel[h, r, p] = q_h[r,:] . rel_emb[p,:]
__global__ __launch_bounds__(256) void qrel_gemm(const uint16_t* __restrict__ QKV,
                                                 const uint16_t* __restrict__ relb,
                                                 uint16_t* __restrict__ qrel) {
    __shared__ char lds[16384];
    char* ldsA = lds;
    char* ldsB = lds + 8192;
    int h = blockIdx.y;
    int r0 = blockIdx.x * 64;
    int t = threadIdx.x, lane = t & 63, w = t >> 6;
    int l15 = lane & 15, lh = lane >> 4;
    {
        int row = t >> 3, ch = t & 7;
        #pragma unroll
        for (int p = 0; p < 2; p++) {
            int r = row + 32 * p;
            bf16x8 v = *(const bf16x8*)(QKV + (size_t)(r0 + r) * QKV_N + h * 64 + ch * 8);
            *(bf16x8*)(ldsA + r * 128 + ((ch * 16) ^ ((r & 7) << 4))) = v;
        }
    }
    __syncthreads();
    bf16x8 afrag[2];
    #pragma unroll
    for (int kk = 0; kk < 2; kk++) {
        int m = w * 16 + l15;
        afrag[kk] = *(const bf16x8*)(ldsA + m * 128 + ((kk * 64 + lh * 16) ^ ((m & 7) << 4)));
    }
    for (int pb = 0; pb < REL_PITCH / 64; pb++) {
        int p0 = pb * 64;
        __syncthreads();
        {
            int row = t >> 3, ch = t & 7;
            #pragma unroll
            for (int p = 0; p < 2; p++) {
                int r = row + 32 * p;
                bf16x8 v = *(const bf16x8*)(relb + (size_t)(p0 + r) * 64 + ch * 8);
                *(bf16x8*)(ldsB + r * 128 + ((ch * 16) ^ ((r & 7) << 4))) = v;
            }
        }
        __syncthreads();
        f32x4 acc[4] = {};
        #pragma unroll
        for (int kk = 0; kk < 2; kk++)
            #pragma unroll
            for (int ni = 0; ni < 4; ni++) {
                int n = ni * 16 + l15;
                bf16x8 b = *(const bf16x8*)(ldsB + n * 128 + ((kk * 64 + lh * 16) ^ ((n & 7) << 4)));
                acc[ni] = __builtin_amdgcn_mfma_f32_16x16x32_bf16(afrag[kk], b, acc[ni], 0, 0, 0);
            }
        #pragma unroll
        for (int ni = 0; ni < 4; ni++)
            #pragma unroll
            for (int i = 0; i < 4; i++) {
                int rr = r0 + w * 16 + lh * 4 + i;
                int p = p0 + ni * 16 + l15;
                qrel[((size_t)h * NROWS + rr) * REL_PITCH + p] = f2bf(acc[ni][i]);
            }
    }
}

// ---------------------------------------------------------------- flash attention (R4 skeleton +
//   XCD-chunked remap for K/V L2 reuse + depth-2 prefetch of K/V regs and qrel gathers)
__global__ __launch_bounds__(512, 4) void attn_kernel(const uint16_t* __restrict__ QKV,
                                                      const uint16_t* __restrict__ qrel,
                                                      float* __restrict__ Opart,
                                                      float* __restrict__ mlpart) {
    __shared__ char lds[53248];   // [0:16K) Q then P(8x2K) | 2 x (K 8K + V^T 10K)
    char* ldsQ = lds;
    char* ldsKV = lds + 16384;

    // XCD-chunked bijective remap (512 blocks): XCD r owns x in [64r, 64r+64) =
    // 4 complete (h,z) groups of 16 q-blocks -> each 256KB K/V slice is L2-resident on one XCD.
    int flat = blockIdx.x + 16 * (blockIdx.y + 8 * blockIdx.z);   // 512 blocks
    int x = (flat & 7) * 64 + (flat >> 3);
    int qb = x & 15, h = (x >> 4) & 7, z = x >> 7;
    int b = z >> 1, sp = z & 1;

    int t = threadIdx.x, lane = t & 63, w = t >> 6;
    int l15 = lane & 15, lh = lane >> 4;
    int row = t >> 3, ch = t & 7;
    int n0 = qb * 128;
    int kvbase = sp * KV_PER_SPLIT;
    size_t rowQ = (size_t)b * NSEQ + n0;

    // ---- V^T constant rows 64..79: row 64 = ones (l-column), 65..79 = zeros; both buffers
    {
        int buf = t >> 8, idx = t & 255;            // 256 threads per buffer, 8B each
        uint32_t val = (idx < 16) ? 0x3F803F80u : 0u;
        char* p = ldsKV + buf * 18432 + 8192 + 8192 + (idx >> 4) * 128 + (idx & 15) * 8;
        *(uint32_t*)(p) = val;
        *(uint32_t*)(p + 4) = val;
    }

    // ---- stage Q tile 128x64 (swizzled) ----
    #pragma unroll
    for (int p = 0; p < 2; p++) {
        int r = row + 64 * p;
        bf16x8 v = *(const bf16x8*)(QKV + (rowQ + r) * QKV_N + h * 64 + ch * 8);
        *(bf16x8*)(ldsQ + r * 128 + ((ch * 16) ^ ((r & 7) << 4))) = v;
    }
    __syncthreads();
    bf16x8 qf[2];
    #pragma unroll
    for (int kk = 0; kk < 2; kk++) {
        int m = w * 16 + l15;
        qf[kk] = *(const bf16x8*)(ldsQ + m * 128 + ((kk * 64 + lh * 16) ^ ((m & 7) << 4)));
    }
    char* myP = ldsQ + w * 2048;      // P overlays dead Q region (per-wave 2KB)

    f32x4 oacc[5] = {};               // [0..3] = O cols, [4] = l-column (col 64)
    float mrow[4];
    #pragma unroll
    for (int i = 0; i < 4; i++) mrow[i] = -INFINITY;

    const uint16_t* qbase = qrel + ((size_t)h * NROWS + (size_t)b * NSEQ) * REL_PITCH;
    uint32_t rowbase[4];              // n_i * REL_PITCH + 512 (center d=0)
    #pragma unroll
    for (int i = 0; i < 4; i++) rowbase[i] = (uint32_t)(n0 + w * 16 + lh * 4 + i) * REL_PITCH + 512;

    auto load_kv = [&](int tile, bf16x8& kr, bf16x8& vr) {
        size_t gro = ((size_t)b * NSEQ + kvbase + tile * 64 + row) * QKV_N + h * 64 + ch * 8;
        kr = *(const bf16x8*)(QKV + gro + 512);
        vr = *(const bf16x8*)(QKV + gro + 1024);
    };
    auto scatter_kv = [&](int tile, bf16x8& kr, bf16x8& vr) {
        char* ldsK = ldsKV + (tile & 1) * 18432;
        char* ldsV = ldsK + 8192;
        *(bf16x8*)(ldsK + row * 128 + ((ch * 16) ^ ((row & 7) << 4))) = kr;
        #pragma unroll
        for (int dd = 0; dd < 8; dd++) {
            int d = ch * 8 + dd;
            int s = dd ^ ch;          // (d&7) ^ ((d>>3)&7)
            *(uint16_t*)(ldsV + d * 128 + 2 * (row ^ (s << 3))) = (uint16_t)vr[dd];
        }
    };
    auto load_g = [&](int tile, uint16_t* g) {
        int kv0 = kvbase + tile * 64;
        int rel0 = n0 - kv0;          // block-uniform
        if (rel0 <= -640) {           // all dist <= -512
            #pragma unroll
            for (int i = 0; i < 4; i++) {
                uint16_t v = qbase[rowbase[i] - 512];
                #pragma unroll
                for (int nf = 0; nf < 4; nf++) g[nf * 4 + i] = v;
            }
        } else if (rel0 >= 576) {     // all dist >= 512
            #pragma unroll
            for (int i = 0; i < 4; i++) {
                uint16_t v = qbase[rowbase[i] + 512];
                #pragma unroll
                for (int nf = 0; nf < 4; nf++) g[nf * 4 + i] = v;
            }
        } else {
            #pragma unroll
            for (int i = 0; i < 4; i++) {
                int nmk = (n0 + w * 16 + lh * 4 + i) - kv0;
                #pragma unroll
                for (int nf = 0; nf < 4; nf++) {
                    int d = nmk - (nf * 16 + l15);
                    d = d < -512 ? -512 : (d > 512 ? 512 : d);
                    g[nf * 4 + i] = qbase[rowbase[i] + d];
                }
            }
        }
    };

    const int NT = KV_PER_SPLIT / 64;   // 16
    uint16_t gA[16], gB[16];
    bf16x8 krA, vrA, krB, vrB;

    // prologue: tile 0 staged; tile 1 in flight
    load_kv(0, krA, vrA);
    load_g(0, gA);
    scatter_kv(0, krA, vrA);
    load_kv(1, krB, vrB);
    load_g(1, gB);

    // body(tt): buf[tt&1] holds tile tt. Issue loads for tt+2 into the set freed by
    // scatter(tt) (= self set), reload g after its consumption, scatter tt+1 from other set.
    auto body = [&](int tt, bf16x8& kS, bf16x8& vS, uint16_t* gS, bf16x8& kO, bf16x8& vO) {
        char* ldsK = ldsKV + (tt & 1) * 18432;
        char* ldsV = ldsK + 8192;
        __syncthreads();                               // tile tt visible
        if (tt + 2 < NT) load_kv(tt + 2, kS, vS);      // depth-2 global prefetch

        // S = Q K^T
        f32x4 sacc[4] = {};
        __builtin_amdgcn_s_setprio(1);
        #pragma unroll
        for (int kk = 0; kk < 2; kk++)
            #pragma unroll
            for (int nf = 0; nf < 4; nf++) {
                int n = nf * 16 + l15;
                bf16x8 kfv = *(const bf16x8*)(ldsK + n * 128 + ((kk * 64 + lh * 16) ^ ((n & 7) << 4)));
                sacc[nf] = __builtin_amdgcn_mfma_f32_16x16x32_bf16(qf[kk], kfv, sacc[nf], 0, 0, 0);
            }
        __builtin_amdgcn_s_setprio(0);

        // + relative-position bias (raw, unscaled), then reload gS for tile tt+2
        #pragma unroll
        for (int nf = 0; nf < 4; nf++)
            #pragma unroll
            for (int i = 0; i < 4; i++)
                sacc[nf][i] += bf2f(gS[nf * 4 + i]);
        if (tt + 2 < NT) load_g(tt + 2, gS);           // depth-2 L3 gather prefetch

        // defer-max gate: zero cross-lane ops on the common path
        float lmax = sacc[0][0];
        #pragma unroll
        for (int nf = 0; nf < 4; nf++)
            #pragma unroll
            for (int i = 0; i < 4; i++) lmax = fmaxf(lmax, sacc[nf][i]);
        float mmin = fminf(fminf(mrow[0], mrow[1]), fminf(mrow[2], mrow[3]));
        if (!__all(lmax <= mmin + 64.0f)) {   // rare: accurate row maxes + rescale
            #pragma unroll
            for (int i = 0; i < 4; i++) {
                float mx = fmaxf(fmaxf(sacc[0][i], sacc[1][i]), fmaxf(sacc[2][i], sacc[3][i]));
                mx = fmaxf(mx, __shfl_xor(mx, 1));
                mx = fmaxf(mx, __shfl_xor(mx, 2));
                mx = fmaxf(mx, __shfl_xor(mx, 4));
                mx = fmaxf(mx, __shfl_xor(mx, 8));
                float mnew = fmaxf(mrow[i], mx);
                float alpha = exp2f((mrow[i] - mnew) * SCALE_LOG2E);
                mrow[i] = mnew;
                #pragma unroll
                for (int nf = 0; nf < 5; nf++) oacc[nf][i] *= alpha;
            }
        }

        // P = exp2((S - m)*c) -> bf16 (cvt_pk RTNE) -> LDS
        #pragma unroll
        for (int i = 0; i < 4; i++) {
            int r = lh * 4 + i;
            int rsw = (r & 7) << 4;
            #pragma unroll
            for (int nf = 0; nf < 4; nf++) {
                float p = exp2f((sacc[nf][i] - mrow[i]) * SCALE_LOG2E);
                uint32_t pb;
                asm("v_cvt_pk_bf16_f32 %0, %1, %2" : "=v"(pb) : "v"(p), "v"(p));
                *(uint16_t*)(myP + r * 128 + (((nf * 16 + l15) * 2) ^ rsw)) = (uint16_t)pb;
            }
        }

        asm volatile("s_waitcnt lgkmcnt(0)" ::: "memory");
        __builtin_amdgcn_sched_barrier(0);
        __builtin_amdgcn_s_setprio(1);
        #pragma unroll
        for (int kk = 0; kk < 2; kk++) {
            bf16x8 pa = *(const bf16x8*)(myP + l15 * 128 + ((kk * 64 + lh * 16) ^ ((l15 & 7) << 4)));
            #pragma unroll
            for (int nf = 0; nf < 5; nf++) {      // nf==4: ones row -> l
                int d = nf * 16 + l15;
                int sd = (d & 7) ^ ((d >> 3) & 7);
                bf16x8 vb = *(const bf16x8*)(ldsV + d * 128 + 16 * ((kk * 4 + lh) ^ sd));
                oacc[nf] = __builtin_amdgcn_mfma_f32_16x16x32_bf16(pa, vb, oacc[nf], 0, 0, 0);
            }
        }
        __builtin_amdgcn_s_setprio(0);

        if (tt + 1 < NT) scatter_kv(tt + 1, kO, vO);   // into buf[(tt+1)&1]; dbuf -> no 2nd barrier
    };

    #pragma unroll 1
    for (int tt2 = 0; tt2 < NT; tt2 += 2) {
        body(tt2,     krA, vrA, gA, krB, vrB);
        body(tt2 + 1, krB, vrB, gB, krA, vrA);
    }

    // epilogue: unnormalized partial O (f32) + m/l per row (l lives in oacc[4], col 64 -> l15==0)
    size_t rbase = ((size_t)(sp * BATCH + b) * HEADS + h) * NSEQ;
    #pragma unroll
    for (int nf = 0; nf < 4; nf++)
        #pragma unroll
        for (int i = 0; i < 4; i++) {
            int r = n0 + w * 16 + lh * 4 + i;
            Opart[(rbase + r) * 64 + nf * 16 + l15] = oacc[nf][i];
        }
    if (l15 == 0) {
        #pragma unroll
        for (int i = 0; i < 4; i++) {
            int r = n0 + w * 16 + lh * 4 + i;
            mlpart[(rbase + r) * 2]     = mrow[i];
            mlpart[(rbase + r) * 2 + 1] = oacc[4][i];
        }
    }
}

// ---------------------------------------------------------------- combine the 2 KV-splits
__global__ __launch_bounds__(256) void combine_kernel(const float* __restrict__ Opart,
                                                      const float* __restrict__ mlpart,
                                                      uint16_t* __restrict__ attO) {
    int lane = threadIdx.x & 63;
    int R = blockIdx.x * 4 + (threadIdx.x >> 6);   // [0, 32768): (b*8+h)*2048 + n
    const int SPSTRIDE = BATCH * HEADS * NSEQ;     // 32768
    float m1 = mlpart[(size_t)R * 2], l1 = mlpart[(size_t)R * 2 + 1];
    float m2 = mlpart[((size_t)SPSTRIDE + R) * 2], l2 = mlpart[((size_t)SPSTRIDE + R) * 2 + 1];
    float M = fmaxf(m1, m2);
    float w1 = exp2f((m1 - M) * SCALE_LOG2E);
    float w2 = exp2f((m2 - M) * SCALE_LOG2E);
    float Linv = 1.f / (l1 * w1 + l2 * w2);
    float o1 = Opart[(size_t)R * 64 + lane];
    float o2 = Opart[((size_t)SPSTRIDE + R) * 64 + lane];
    float o = (o1 * w1 + o2 * w2) * Linv;
    int bh = R >> 11, n = R & 2047;
    int b = bh >> 3, hh = bh & 7;
    attO[((size_t)(b * NSEQ + n)) * DIM + hh * 64 + lane] = f2bf(o);
}

// ---------------------------------------------------------------- launch
extern "C" void kernel_launch(void* const* d_in, const int* in_sizes, int n_in,
                              void* d_out, int out_size, void* d_ws, size_t ws_size,
                              hipStream_t stream) {
    const float* x   = (const float*)d_in[0];
    const float* Wq  = (const float*)d_in[1];
    const float* Wkv = (const float*)d_in[2];
    const float* Wo  = (const float*)d_in[3];
    const float* bo  = (const float*)d_in[4];
    const float* rel = (const float*)d_in[5];
    char* ws = (char*)d_ws;
    uint16_t* Xb     = (uint16_t*)(ws);                 // 4096*512*2      = 4,194,304 (dead after QKV gemm)
    float*    mlp    = (float*)(ws);                    // 65536*2*4      = 524,288 (reuses Xb region)
    uint16_t* Wqkv_t = (uint16_t*)(ws + 4194304);       // 1536*512*2     = 1,572,864
    uint16_t* Wo_t   = (uint16_t*)(ws + 5767168);       // 512*512*2      = 524,288
    uint16_t* relb   = (uint16_t*)(ws + 6291456);       // 1088*64*2      = 139,264
    uint16_t* QKV    = (uint16_t*)(ws + 6430720);       // 4096*1536*2    = 12,582,912
    uint16_t* attO   = (uint16_t*)(ws + 19013632);      // 4096*512*2     = 4,194,304
    uint16_t* qrel   = (uint16_t*)(ws + 23207936);      // 8*4096*1088*2  = 71,303,168
    float*    Opart  = (float*)(ws + 94511104);         // 2*32768*64*4   = 16,777,216  (end 111,288,320)

    prep_misc<<<2048, 256, 0, stream>>>(x, rel, Xb, relb);
    prep_w<<<1024, 256, 0, stream>>>(Wq, Wkv, Wo, Wqkv_t, Wo_t);
    gemm128<true><<<dim3(32, 12), 256, 0, stream>>>(Xb, Wqkv_t, QKV, nullptr, 512, QKV_N);
    qrel_gemm<<<dim3(64, 8), 256, 0, stream>>>(QKV, relb, qrel);
    attn_kernel<<<dim3(16, 8, 4), 512, 0, stream>>>(QKV, qrel, Opart, mlp);
    combine_kernel<<<8192, 256, 0, stream>>>(Opart, mlp, attO);
    gemm128<false><<<dim3(32, 4), 256, 0, stream>>>(attO, Wo_t, (float*)d_out, bo, 512, DIM);
}